// Round 1
// 179.080 us; speedup vs baseline: 1.0176x; 1.0176x over previous
//
#include <hip/hip_runtime.h>

#define B_TOT 65536
#define R 12
#define L 16
#define NB 16
#define NEG_MIN -3.402823466e38f

// ws layout (float index):
//   [0,32)   v[j]  (kw2 . qb2)
//   [32]     c     (qb2 . kb2)
//   [40,52)  pmask (as int: bit l set if freq_mask[r][l] != 0)
//   [64,96)  sorted breakpoints t[32]
//   [96, 96+33*72) interval table: row m (72 floats, 288 B):
//        [0,32) A_m   [32] Au_m   [33,36) pad
//        [36,68) B_m  [68] Bu_m   [69,72) pad
#define WS_V   0
#define WS_C   32
#define WS_PM  40
#define WS_BP  64
#define WS_TAB 96
#define TROW   72

typedef __attribute__((ext_vector_type(8))) short short8;
typedef __attribute__((ext_vector_type(4))) float f32x4;

static __device__ __forceinline__ short f2bf(float f) {
    uint32_t u = __float_as_uint(f);
    uint32_t r = u + 0x7FFFu + ((u >> 16) & 1u);  // round-to-nearest-even
    return (short)(r >> 16);
}

// HW packed f32->bf16 (RNE), 1 instruction for 2 elements.
// dst.lo16 = bf16(a), dst.hi16 = bf16(b) -- same rounding as f2bf.
static __device__ __forceinline__ unsigned cvt_pk_bf16(float a, float b) {
    unsigned d;
    asm("v_cvt_pk_bf16_f32 %0, %1, %2" : "=v"(d) : "v"(a), "v"(b));
    return d;
}

__global__ __launch_bounds__(256) void nfh_pre(
    const float* __restrict__ qw1, const float* __restrict__ qb1,
    const float* __restrict__ qw2, const float* __restrict__ qb2,
    const float* __restrict__ kw2, const float* __restrict__ kb2,
    const int*   __restrict__ fmask,
    float* __restrict__ ws)
{
    __shared__ float sM[1024];
    __shared__ float su[32];
    __shared__ float sw1[32], sb1[32], sbp[32];
    const int t = threadIdx.x;

    if (t < 32) { sw1[t] = qw1[t]; sb1[t] = qb1[t]; }
    for (int e = t; e < 1024; e += 256) {
        const int i = e >> 5, j = e & 31;
        float acc = 0.f;
        for (int h = 0; h < 64; ++h) acc = fmaf(qw2[i * 64 + h], kw2[j * 64 + h], acc);
        sM[e] = acc;
    }
    if (t < 32) {
        float au = 0.f, av = 0.f;
        for (int h = 0; h < 64; ++h) {
            au = fmaf(qw2[t * 64 + h], kb2[h], au);
            av = fmaf(kw2[t * 64 + h], qb2[h], av);
        }
        su[t] = au;
        ws[WS_V + t] = av;
        const float w = qw1[t];
        sbp[t] = (w != 0.f) ? (-qb1[t] / w) : 3.0e30f;
    }
    if (t == 64) {
        float acc = 0.f;
        for (int h = 0; h < 64; ++h) acc = fmaf(qb2[h], kb2[h], acc);
        ws[WS_C] = acc;
    }
    if (t < 12) {
        int pm = 0;
        for (int l = 0; l < 16; ++l) if (fmask[t * 16 + l] != 0) pm |= (1 << l);
        ((int*)ws)[WS_PM + t] = pm;
    }
    __syncthreads();
    if (t == 0) {
        for (int i = 1; i < 32; ++i) {
            float key = sbp[i]; int j = i - 1;
            while (j >= 0 && sbp[j] > key) { sbp[j + 1] = sbp[j]; --j; }
            sbp[j + 1] = key;
        }
    }
    __syncthreads();
    if (t < 32) ws[WS_BP + t] = sbp[t];

    for (int task = t; task < 33 * 32 + 33; task += 256) {
        const int m = (task < 33 * 32) ? (task >> 5) : (task - 33 * 32);
        const float xi = (m == 0) ? sbp[0] - 1.f
                       : ((m == 32) ? sbp[31] + 1.f
                                    : sbp[m - 1] + 0.5f * (sbp[m] - sbp[m - 1]));
        if (task < 33 * 32) {
            const int j = task & 31;
            float A = 0.f, Bv = 0.f;
            for (int i = 0; i < 32; ++i) {
                if (fmaf(sw1[i], xi, sb1[i]) > 0.f) {
                    A  = fmaf(sw1[i], sM[i * 32 + j], A);
                    Bv = fmaf(sb1[i], sM[i * 32 + j], Bv);
                }
            }
            ws[WS_TAB + m * TROW + j] = A;
            ws[WS_TAB + m * TROW + 36 + j] = Bv;
        } else {
            float Au = 0.f, Bu = 0.f;
            for (int i = 0; i < 32; ++i) {
                if (fmaf(sw1[i], xi, sb1[i]) > 0.f) {
                    Au = fmaf(sw1[i], su[i], Au);
                    Bu = fmaf(sb1[i], su[i], Bu);
                }
            }
            ws[WS_TAB + m * TROW + 32] = Au;
            ws[WS_TAB + m * TROW + 36 + 32] = Bu;
        }
    }
}

__global__ __launch_bounds__(256, 5) void nfh_main(
    const float* __restrict__ rss,   // [B,R]
    const float* __restrict__ feat,  // [B,L,F]
    const float* __restrict__ pos,   // [B,L,3]
    const float* __restrict__ prev,  // [B,3]
    const float* __restrict__ gw1, const float* __restrict__ gb1,
    const float* __restrict__ gw2, const float* __restrict__ gb2,
    const float* __restrict__ kw1, const float* __restrict__ kb1,
    const float* __restrict__ sigma_p,
    const float* __restrict__ ws,
    float* __restrict__ out)
{
    // MFMA operand fragments, built directly in lane order:
    // A-frag (bh):  lane = kblock*16 + l, holds bh[l][kblock*8 .. +7]
    // B-frag (tt):  lane = kblock*16 + r (r<12 only stored), holds tt[r][kblock*8 .. +7]
    __shared__ short s_bhf[NB * 512];  // 16 KB
    __shared__ short s_ttf[NB * 384];  // 12 KB (12 real rows per kblock; r>=12 zeroed in regs)
    __shared__ float s_vb[NB * 16];
    __shared__ float s_tc[NB * 12];
    __shared__ int   s_pm[16];

    const int t = threadIdx.x;
    const int b0 = blockIdx.x * NB;
    const float sigma = sigma_p[0];
    const float inv2s2 = 1.f / (2.f * sigma * sigma);

    if (t < 16) s_pm[t] = (t < 12) ? ((const int*)ws)[WS_PM + t] : 0;

    // ---------- P1: all 256 threads = (bb1, l1): key MLP -> bf16 A-frag ----------
    {
        const int bb1 = t >> 4, l1 = t & 15;
        const int b = b0 + bb1;
        float in[11];
        const float4* f4 = (const float4*)(feat + ((size_t)b * (L * 8) + l1 * 8));
        const float4 fa = f4[0], fb = f4[1];
        in[0] = fa.x; in[1] = fa.y; in[2] = fa.z; in[3] = fa.w;
        in[4] = fb.x; in[5] = fb.y; in[6] = fb.z; in[7] = fb.w;
        const float* pp = pos + ((size_t)b * (L * 3) + l1 * 3);
        in[8] = pp[0]; in[9] = pp[1]; in[10] = pp[2];

        float dsq = 0.f;
        #pragma unroll
        for (int m = 0; m < 3; ++m) {
            const float d = prev[b * 3 + m] - in[8 + m];
            dsq = fmaf(d, d, dsq);
        }
        float bh[32];
        #pragma unroll
        for (int j = 0; j < 32; ++j) bh[j] = kb1[j];
        #pragma unroll
        for (int m = 0; m < 11; ++m) {
            const float im = in[m];
            #pragma unroll
            for (int j = 0; j < 32; ++j) bh[j] = fmaf(im, kw1[m * 32 + j], bh[j]);
        }
        float vb = ws[WS_C];
        #pragma unroll
        for (int j = 0; j < 32; ++j) {
            bh[j] = fmaxf(bh[j], 0.f);
            vb = fmaf(ws[WS_V + j], bh[j], vb);
        }
        s_vb[bb1 * 16 + l1] = vb - dsq * inv2s2;

        #pragma unroll
        for (int kb = 0; kb < 4; ++kb) {
            uint4 pk;
            pk.x = cvt_pk_bf16(bh[kb * 8 + 0], bh[kb * 8 + 1]);
            pk.y = cvt_pk_bf16(bh[kb * 8 + 2], bh[kb * 8 + 3]);
            pk.z = cvt_pk_bf16(bh[kb * 8 + 4], bh[kb * 8 + 5]);
            pk.w = cvt_pk_bf16(bh[kb * 8 + 6], bh[kb * 8 + 7]);
            *(uint4*)&s_bhf[bb1 * 512 + (kb * 16 + l1) * 8] = pk;
        }
    }

    // ---------- P2a: t < 192 = (bb2, r2): gate -> iw, tt lookup -> bf16 B-frag ----
    if (t < NB * R) {
        const int bb2 = t / R;
        const int r2 = t - bb2 * R;
        const float x = rss[(size_t)b0 * R + t];
        float z = gb2[0];
        #pragma unroll
        for (int i = 0; i < 16; ++i) {
            const float h = fmaxf(fmaf(x, gw1[i], gb1[i]), 0.f);
            z = fmaf(h, gw2[i], z);
        }
        const float gate = 1.f / (1.f + __expf(-z));
        const float iw = (x > 0.5f) ? gate : 0.f;
        out[(size_t)B_TOT * R * L + (size_t)b0 * R + t] = iw;
        const float xq = x * iw;

        int k = 0;
        #pragma unroll
        for (int m = 0; m < 32; ++m) k += (xq > ws[WS_BP + m]) ? 1 : 0;
        const float* row = ws + WS_TAB + k * TROW;
        const float4* ra = (const float4*)row;
        const float4* rb = (const float4*)(row + 36);
        s_tc[bb2 * 12 + r2] = fmaf(xq, row[32], row[68]);
        #pragma unroll
        for (int kb = 0; kb < 4; ++kb) {
            const float4 a0 = ra[kb * 2], c0 = rb[kb * 2];
            const float4 a1 = ra[kb * 2 + 1], c1 = rb[kb * 2 + 1];
            uint4 pk;
            pk.x = cvt_pk_bf16(fmaf(xq, a0.x, c0.x), fmaf(xq, a0.y, c0.y));
            pk.y = cvt_pk_bf16(fmaf(xq, a0.z, c0.z), fmaf(xq, a0.w, c0.w));
            pk.z = cvt_pk_bf16(fmaf(xq, a1.x, c1.x), fmaf(xq, a1.y, c1.y));
            pk.w = cvt_pk_bf16(fmaf(xq, a1.z, c1.z), fmaf(xq, a1.w, c1.w));
            *(uint4*)&s_ttf[bb2 * 384 + (kb * 12 + r2) * 8] = pk;
        }
    }
    __syncthreads();

    // ---------- P3: wave w handles batches w*4 .. w*4+3: 1 MFMA each ----------
    {
        const int lane = t & 63;
        const int w = t >> 6;
        const int r = lane & 15;
        const int lg = lane >> 4;
        const int pm = s_pm[r];

        #pragma unroll
        for (int i = 0; i < 4; ++i) {
            const int bb = w * 4 + i;
            const short8 af = *(const short8*)&s_bhf[bb * 512 + lane * 8];
            short8 bf = (short8){0, 0, 0, 0, 0, 0, 0, 0};
            float tc = 0.f;
            if (r < R) {
                bf = *(const short8*)&s_ttf[bb * 384 + (lg * 12 + r) * 8];
                tc = s_tc[bb * 12 + r];
            }
            f32x4 acc = {0.f, 0.f, 0.f, 0.f};
            acc = __builtin_amdgcn_mfma_f32_16x16x32_bf16(af, bf, acc, 0, 0, 0);

            const f32x4 vb4 = *(const f32x4*)&s_vb[bb * 16 + lg * 4];

            float sc[4];
            #pragma unroll
            for (int j = 0; j < 4; ++j) {
                sc[j] = acc[j] + tc + vb4[j];
                if (!((pm >> (lg * 4 + j)) & 1)) sc[j] = NEG_MIN;
            }
            float mx = fmaxf(fmaxf(sc[0], sc[1]), fmaxf(sc[2], sc[3]));
            mx = fmaxf(mx, __shfl_xor(mx, 16));
            mx = fmaxf(mx, __shfl_xor(mx, 32));
            float sum = 0.f;
            #pragma unroll
            for (int j = 0; j < 4; ++j) { sc[j] = __expf(sc[j] - mx); sum += sc[j]; }
            sum += __shfl_xor(sum, 16);
            sum += __shfl_xor(sum, 32);
            const float inv = 1.f / sum;

            if (r < R) {
                float4* op = (float4*)(out + ((size_t)(b0 + bb) * R + r) * L + lg * 4);
                *op = make_float4(sc[0] * inv, sc[1] * inv, sc[2] * inv, sc[3] * inv);
            }
        }
    }
}

extern "C" void kernel_launch(void* const* d_in, const int* in_sizes, int n_in,
                              void* d_out, int out_size, void* d_ws, size_t ws_size,
                              hipStream_t stream) {
    const float* rss   = (const float*)d_in[0];
    const float* feat  = (const float*)d_in[1];
    const float* pos   = (const float*)d_in[2];
    const float* prev  = (const float*)d_in[3];
    const int*   fmask = (const int*)d_in[4];
    const float* gw1   = (const float*)d_in[5];
    const float* gb1   = (const float*)d_in[6];
    const float* gw2   = (const float*)d_in[7];
    const float* gb2   = (const float*)d_in[8];
    const float* qw1   = (const float*)d_in[9];
    const float* qb1   = (const float*)d_in[10];
    const float* qw2   = (const float*)d_in[11];
    const float* qb2   = (const float*)d_in[12];
    const float* kw1   = (const float*)d_in[13];
    const float* kb1   = (const float*)d_in[14];
    const float* kw2   = (const float*)d_in[15];
    const float* kb2   = (const float*)d_in[16];
    const float* sigma = (const float*)d_in[17];
    float* out = (float*)d_out;
    float* ws  = (float*)d_ws;

    nfh_pre<<<1, 256, 0, stream>>>(qw1, qb1, qw2, qb2, kw2, kb2, fmask, ws);
    nfh_main<<<B_TOT / NB, 256, 0, stream>>>(
        rss, feat, pos, prev,
        gw1, gb1, gw2, gb2, kw1, kb1,
        sigma, ws, out);
}